// Round 1
// baseline (259.640 us; speedup 1.0000x reference)
//
#include <hip/hip_runtime.h>
#include <hip/hip_bf16.h>
#include <stdint.h>

typedef __attribute__((ext_vector_type(8))) short short8;
typedef __attribute__((ext_vector_type(4))) float f32x4;

#define B_   4
#define N_   4096
#define C_   256
#define DQK  32
#define DV   128
#define NCOL 192      // DQK + DQK + DV
#define QBLK 64
#define KVB  64
#define NT   (N_/KVB) // 64
#define PROWB 144     // P_lds row stride in bytes (72 bf16; 2-way conflict max)

__device__ __forceinline__ uint16_t f2bf(float f) {
    uint32_t u = __float_as_uint(f);
    u += 0x7fffu + ((u >> 16) & 1u);   // RNE
    return (uint16_t)(u >> 16);
}

// ---------------------------------------------------------------------------
// K0: cast + transpose weights.  WfghT[192][256] bf16 (cols of Wf|Wg|Wh),
//     WvT[256][128] bf16 (cols of Wv).
// ---------------------------------------------------------------------------
__global__ __launch_bounds__(256) void prep_weights(
    const float* __restrict__ Wf, const float* __restrict__ Wg,
    const float* __restrict__ Wh, const float* __restrict__ Wv,
    uint16_t* __restrict__ WfghT, uint16_t* __restrict__ WvT)
{
    int idx = blockIdx.x * 256 + threadIdx.x;
    if (idx < NCOL * C_) {
        int c = idx / C_, k = idx % C_;
        float v = (c < DQK)   ? Wf[k * DQK + c]
                : (c < 2*DQK) ? Wg[k * DQK + (c - DQK)]
                              : Wh[k * DV  + (c - 2*DQK)];
        WfghT[idx] = f2bf(v);
    }
    int idx2 = idx - NCOL * C_;
    if (idx2 >= 0 && idx2 < C_ * DV) {
        int c = idx2 / DV, k = idx2 % DV;
        WvT[idx2] = f2bf(Wv[k * C_ + c]);
    }
}

// ---------------------------------------------------------------------------
// K1: projection GEMM  [16384 x 256] @ [256 x 192] (bf16 MFMA, f32 acc)
//     writes fK [b][n][32], gQ [b][n][32] row-major bf16,
//     and    vT [b][128][4096] (transposed values) bf16.
// ---------------------------------------------------------------------------
__global__ __launch_bounds__(256) void proj_kernel(
    const float* __restrict__ x, const uint16_t* __restrict__ WfghT,
    const float* __restrict__ bf, const float* __restrict__ bg,
    const float* __restrict__ bh,
    uint16_t* __restrict__ fK, uint16_t* __restrict__ gQ,
    uint16_t* __restrict__ vT)
{
    const int lane = threadIdx.x & 63;
    const int w    = threadIdx.x >> 6;
    const int rb   = blockIdx.x * 64 + w * 16;   // 16 rows per wave
    const int lr   = lane & 15, lg = lane >> 4;
    const int arow = rb + lr;

    const f32x4 z = {0.f, 0.f, 0.f, 0.f};
    f32x4 acc[12];
#pragma unroll
    for (int i = 0; i < 12; ++i) acc[i] = z;

#pragma unroll
    for (int kc = 0; kc < 8; ++kc) {
        // A-frag: x[arow][kc*32 + lg*8 .. +7]  (f32 -> bf16)
        const float* ap = x + (size_t)arow * C_ + kc * 32 + lg * 8;
        f32x4 u0 = *(const f32x4*)ap;
        f32x4 u1 = *(const f32x4*)(ap + 4);
        short8 a;
        a[0]=(short)f2bf(u0[0]); a[1]=(short)f2bf(u0[1]);
        a[2]=(short)f2bf(u0[2]); a[3]=(short)f2bf(u0[3]);
        a[4]=(short)f2bf(u1[0]); a[5]=(short)f2bf(u1[1]);
        a[6]=(short)f2bf(u1[2]); a[7]=(short)f2bf(u1[3]);
#pragma unroll
        for (int ct = 0; ct < 12; ++ct) {
            short8 b = *(const short8*)(WfghT + (ct*16 + lr) * C_ + kc*32 + lg*8);
            acc[ct] = __builtin_amdgcn_mfma_f32_16x16x32_bf16(a, b, acc[ct], 0, 0, 0);
        }
    }

#pragma unroll
    for (int ct = 0; ct < 12; ++ct) {
        int col = ct * 16 + lr;
        float bias = (col < DQK)   ? bf[col]
                   : (col < 2*DQK) ? bg[col - DQK]
                                   : bh[col - 2*DQK];
#pragma unroll
        for (int i = 0; i < 4; ++i) {
            int row = rb + lg * 4 + i;           // C layout: row=(lane>>4)*4+reg
            uint16_t h = f2bf(acc[ct][i] + bias);
            if (col < DQK) {
                fK[(size_t)row * DQK + col] = h;
            } else if (col < 2*DQK) {
                gQ[(size_t)row * DQK + (col - DQK)] = h;
            } else {
                int vc = col - 2*DQK;
                int b_ = row >> 12, n = row & (N_ - 1);
                vT[((size_t)b_ * DV + vc) * N_ + n] = h;
            }
        }
    }
}

// ---------------------------------------------------------------------------
// K2: flash attention.  grid=256 (XCD-swizzled: b = (bid&7)>>1), 4 waves,
//     16 q-rows/wave, KV tiles of 64, double-buffered global_load_lds staging
//     with counted vmcnt, XOR-swizzled K/V LDS slots (swizzle on SOURCE addr).
// ---------------------------------------------------------------------------
__global__ __launch_bounds__(256) void attn_kernel(
    const uint16_t* __restrict__ fK, const uint16_t* __restrict__ gQ,
    const uint16_t* __restrict__ vT, uint16_t* __restrict__ oB)
{
    __shared__ __align__(16) uint8_t lds[2*4096 + 2*16384 + 4*2304];
    uint8_t* Kl = lds;                    // 2 x 4 KB : K tiles [64 keys][32 d]
    uint8_t* Vl = lds + 2*4096;           // 2 x 16 KB: VT tiles [128 vc][64 keys]
    const int lane = threadIdx.x & 63;
    const int w    = threadIdx.x >> 6;
    uint8_t* Pl = lds + 2*4096 + 2*16384 + w * 2304;  // per-wave P [16][72]
    const int lr = lane & 15, lg = lane >> 4;

    const int bid   = blockIdx.x;
    const int xcd   = bid & 7;
    const int b     = xcd >> 1;                   // each XCD-pair-slot = 1 batch
    const int qtile = (xcd & 1) * 32 + (bid >> 3);
    const int qbase = qtile * QBLK;

    // Q A-frag (hoisted): row = lr, k = lg*8+i
    short8 aq = *(const short8*)(gQ + ((size_t)(b*N_ + qbase + w*16 + lr)) * DQK + lg*8);

    const f32x4 z = {0.f, 0.f, 0.f, 0.f};
    f32x4 oa[8];
#pragma unroll
    for (int i = 0; i < 8; ++i) oa[i] = z;
    float m_run[4] = {-1e30f, -1e30f, -1e30f, -1e30f};
    float l_run[4] = {0.f, 0.f, 0.f, 0.f};

    const uint16_t* fbase = fK + (size_t)b * N_ * DQK;
    const uint16_t* vbase = vT + (size_t)b * DV * N_;

    auto STAGE = [&](int buf, int kbase) {
        // K tile: 1 load/wave.  Linear LDS slot s holds (key=s>>2, stored quarter
        // s&3); actual d-group g = (s&3) ^ ((key>>1)&3)  (inverse-swizzled source).
        {
            int s   = w * 64 + lane;
            int key = s >> 2;
            int g   = (s & 3) ^ ((key >> 1) & 3);
            const uint16_t* src = fbase + (size_t)(kbase + key) * DQK + g * 8;
            __builtin_amdgcn_global_load_lds(
                (const __attribute__((address_space(1))) uint32_t*)src,
                (__attribute__((address_space(3))) uint32_t*)(Kl + buf*4096 + w*1024),
                16, 0, 0);
        }
        // V tile: 4 loads/wave. slot s -> (vc=s>>3, stored kslot s&7);
        // actual kslot = (s&7) ^ (vc&7).
#pragma unroll
        for (int q = 0; q < 4; ++q) {
            int s  = w * 256 + q * 64 + lane;
            int vc = s >> 3;
            int ks = (s & 7) ^ (vc & 7);
            const uint16_t* src = vbase + (size_t)vc * N_ + kbase + ks * 8;
            __builtin_amdgcn_global_load_lds(
                (const __attribute__((address_space(1))) uint32_t*)src,
                (__attribute__((address_space(3))) uint32_t*)(Vl + buf*16384 + (w*256 + q*64)*16),
                16, 0, 0);
        }
    };

    auto COMPUTE = [&](int buf) {
        const uint8_t* Kb = Kl + buf * 4096;
        const uint8_t* Vb = Vl + buf * 16384;
        // S = Q K^T  (4 groups of 16 keys)
        f32x4 sf[4];
#pragma unroll
        for (int kg = 0; kg < 4; ++kg) {
            int key   = kg * 16 + lr;                       // B col = key
            int slotK = key * 4 + (lg ^ ((key >> 1) & 3));  // swizzled read
            short8 kb = *(const short8*)(Kb + slotK * 16);
            sf[kg] = __builtin_amdgcn_mfma_f32_16x16x32_bf16(aq, kb, z, 0, 0, 0);
        }
        // online softmax per row i (row = lg*4+i, spread over 16 lanes)
#pragma unroll
        for (int i = 0; i < 4; ++i) {
            float tm = fmaxf(fmaxf(sf[0][i], sf[1][i]), fmaxf(sf[2][i], sf[3][i]));
            tm = fmaxf(tm, __shfl_xor(tm, 1, 16));
            tm = fmaxf(tm, __shfl_xor(tm, 2, 16));
            tm = fmaxf(tm, __shfl_xor(tm, 4, 16));
            tm = fmaxf(tm, __shfl_xor(tm, 8, 16));
            float mn = fmaxf(m_run[i], tm);
            float sc = __expf(m_run[i] - mn);
            m_run[i] = mn;
            float rs = 0.f;
#pragma unroll
            for (int kg = 0; kg < 4; ++kg) {
                float p = __expf(sf[kg][i] - mn);
                sf[kg][i] = p;
                rs += p;
            }
            rs += __shfl_xor(rs, 1, 16);
            rs += __shfl_xor(rs, 2, 16);
            rs += __shfl_xor(rs, 4, 16);
            rs += __shfl_xor(rs, 8, 16);
            l_run[i] = l_run[i] * sc + rs;
#pragma unroll
            for (int ct = 0; ct < 8; ++ct) oa[ct][i] *= sc;
            // C-layout -> LDS (row = lg*4+i, col = kg*16+lr)
#pragma unroll
            for (int kg = 0; kg < 4; ++kg) {
                *(uint16_t*)(Pl + (lg*4 + i) * PROWB + (kg*16 + lr) * 2) = f2bf(sf[kg][i]);
            }
        }
        // PV: O += P[16x64] * V[64x128]
#pragma unroll
        for (int kc = 0; kc < 2; ++kc) {
            short8 pa = *(const short8*)(Pl + lr * PROWB + kc * 64 + lg * 16);
#pragma unroll
            for (int ct = 0; ct < 8; ++ct) {
                int vc    = ct * 16 + lr;
                int ks    = kc * 4 + lg;
                int slotV = vc * 8 + (ks ^ (vc & 7));
                short8 vb = *(const short8*)(Vb + slotV * 16);
                oa[ct] = __builtin_amdgcn_mfma_f32_16x16x32_bf16(pa, vb, oa[ct], 0, 0, 0);
            }
        }
    };

    STAGE(0, 0);
    for (int t = 0; t < NT; ++t) {
        if (t + 1 < NT) {
            STAGE((t + 1) & 1, (t + 1) * KVB);
            asm volatile("s_waitcnt vmcnt(5)" ::: "memory");  // stage(t) done; 5 in flight
        } else {
            asm volatile("s_waitcnt vmcnt(0)" ::: "memory");
        }
        asm volatile("s_barrier" ::: "memory");
        COMPUTE(t & 1);
        asm volatile("s_barrier" ::: "memory");
    }

    // epilogue: normalize, store bf16 o [b][n][128]
#pragma unroll
    for (int i = 0; i < 4; ++i) {
        float inv = 1.f / l_run[i];
        int n = qbase + w * 16 + lg * 4 + i;
        uint16_t* op = oB + ((size_t)(b * N_ + n)) * DV;
#pragma unroll
        for (int ct = 0; ct < 8; ++ct) {
            op[ct * 16 + lr] = f2bf(oa[ct][i] * inv);
        }
    }
}

// ---------------------------------------------------------------------------
// K3: out = x + o @ Wv + bv     ([16384 x 128] @ [128 x 256], f32 out)
// ---------------------------------------------------------------------------
__global__ __launch_bounds__(256) void out_kernel(
    const uint16_t* __restrict__ oB, const uint16_t* __restrict__ WvT,
    const float* __restrict__ x, const float* __restrict__ bv,
    float* __restrict__ out)
{
    const int lane = threadIdx.x & 63;
    const int w    = threadIdx.x >> 6;
    const int rb   = blockIdx.x * 64 + w * 16;
    const int lr   = lane & 15, lg = lane >> 4;

    const f32x4 z = {0.f, 0.f, 0.f, 0.f};
    f32x4 acc[16];
#pragma unroll
    for (int i = 0; i < 16; ++i) acc[i] = z;

#pragma unroll
    for (int kc = 0; kc < 4; ++kc) {
        short8 a = *(const short8*)(oB + (size_t)(rb + lr) * DV + kc*32 + lg*8);
#pragma unroll
        for (int ct = 0; ct < 16; ++ct) {
            short8 bfr = *(const short8*)(WvT + (ct*16 + lr) * DV + kc*32 + lg*8);
            acc[ct] = __builtin_amdgcn_mfma_f32_16x16x32_bf16(a, bfr, acc[ct], 0, 0, 0);
        }
    }
#pragma unroll
    for (int ct = 0; ct < 16; ++ct) {
        int col = ct * 16 + lr;
        float bb = bv[col];
#pragma unroll
        for (int i = 0; i < 4; ++i) {
            size_t idx = (size_t)(rb + lg*4 + i) * C_ + col;
            out[idx] = acc[ct][i] + bb + x[idx];
        }
    }
}

// ---------------------------------------------------------------------------
extern "C" void kernel_launch(void* const* d_in, const int* in_sizes, int n_in,
                              void* d_out, int out_size, void* d_ws, size_t ws_size,
                              hipStream_t stream)
{
    const float* x  = (const float*)d_in[0];
    const float* Wf = (const float*)d_in[1];
    const float* bf = (const float*)d_in[2];
    const float* Wg = (const float*)d_in[3];
    const float* bg = (const float*)d_in[4];
    const float* Wh = (const float*)d_in[5];
    const float* bh = (const float*)d_in[6];
    const float* Wv = (const float*)d_in[7];
    const float* bv = (const float*)d_in[8];
    float* out = (float*)d_out;

    uint8_t* ws = (uint8_t*)d_ws;
    size_t off = 0;
    uint16_t* WfghT = (uint16_t*)(ws + off); off += (size_t)NCOL * C_ * 2;   //  96 KB
    uint16_t* WvT   = (uint16_t*)(ws + off); off += (size_t)C_ * DV * 2;     //  64 KB
    uint16_t* fK    = (uint16_t*)(ws + off); off += (size_t)B_ * N_ * DQK * 2; // 1 MB
    uint16_t* gQ    = (uint16_t*)(ws + off); off += (size_t)B_ * N_ * DQK * 2; // 1 MB
    uint16_t* vT    = (uint16_t*)(ws + off); off += (size_t)B_ * DV * N_ * 2;  // 4 MB
    uint16_t* oB    = (uint16_t*)(ws + off); off += (size_t)B_ * N_ * DV * 2;  // 4 MB

    prep_weights<<<320, 256, 0, stream>>>(Wf, Wg, Wh, Wv, WfghT, WvT);
    proj_kernel <<<256, 256, 0, stream>>>(x, WfghT, bf, bg, bh, fK, gQ, vT);
    attn_kernel <<<256, 256, 0, stream>>>(fK, gQ, vT, oB);
    out_kernel  <<<256, 256, 0, stream>>>(oB, WvT, x, bv, out);
}

// Round 10
// 186.826 us; speedup vs baseline: 1.3897x; 1.3897x over previous
//
#include <hip/hip_runtime.h>
#include <hip/hip_bf16.h>
#include <stdint.h>

typedef __attribute__((ext_vector_type(8))) short short8;
typedef __attribute__((ext_vector_type(4))) float f32x4;

#define B_   4
#define N_   4096
#define C_   256
#define DQK  32
#define DV   128
#define NCOL 192      // DQK + DQK + DV
#define QBLK 64
#define KVB  64
#define TOT  (B_*N_)  // 16384 rows total
#define PROWB 144     // P_lds row stride in bytes (72 bf16; 2-way conflict max)

__device__ __forceinline__ uint16_t f2bf(float f) {
    uint32_t u = __float_as_uint(f);
    u += 0x7fffu + ((u >> 16) & 1u);   // RNE
    return (uint16_t)(u >> 16);
}

// ---------------------------------------------------------------------------
// K0: cast + transpose weights.  WfghT[192][256] bf16 (cols of Wf|Wg|Wh),
//     WvT[256][128] bf16 (cols of Wv).
// ---------------------------------------------------------------------------
__global__ __launch_bounds__(256) void prep_weights(
    const float* __restrict__ Wf, const float* __restrict__ Wg,
    const float* __restrict__ Wh, const float* __restrict__ Wv,
    uint16_t* __restrict__ WfghT, uint16_t* __restrict__ WvT)
{
    int idx = blockIdx.x * 256 + threadIdx.x;
    if (idx < NCOL * C_) {
        int c = idx / C_, k = idx % C_;
        float v = (c < DQK)   ? Wf[k * DQK + c]
                : (c < 2*DQK) ? Wg[k * DQK + (c - DQK)]
                              : Wh[k * DV  + (c - 2*DQK)];
        WfghT[idx] = f2bf(v);
    }
    int idx2 = idx - NCOL * C_;
    if (idx2 >= 0 && idx2 < C_ * DV) {
        int c = idx2 / DV, k = idx2 % DV;
        WvT[idx2] = f2bf(Wv[k * C_ + c]);
    }
}

// ---------------------------------------------------------------------------
// K1: projection GEMM  [16384 x 256] @ [256 x 192] (bf16 MFMA, f32 acc)
//     fK/gQ row-major bf16; vT [b][128][4096] via LDS transpose (coalesced).
// ---------------------------------------------------------------------------
__global__ __launch_bounds__(256) void proj_kernel(
    const float* __restrict__ x, const uint16_t* __restrict__ WfghT,
    const float* __restrict__ bf, const float* __restrict__ bg,
    const float* __restrict__ bh,
    uint16_t* __restrict__ fK, uint16_t* __restrict__ gQ,
    uint16_t* __restrict__ vT)
{
    __shared__ __align__(16) uint16_t vlds[128 * 72];   // [vc][n_local] pad 64->72
    const int lane = threadIdx.x & 63;
    const int w    = threadIdx.x >> 6;
    const int rb   = blockIdx.x * 64 + w * 16;   // 16 rows per wave
    const int lr   = lane & 15, lg = lane >> 4;
    const int arow = rb + lr;

    const f32x4 z = {0.f, 0.f, 0.f, 0.f};
    f32x4 acc[12];
#pragma unroll
    for (int i = 0; i < 12; ++i) acc[i] = z;

#pragma unroll
    for (int kc = 0; kc < 8; ++kc) {
        const float* ap = x + (size_t)arow * C_ + kc * 32 + lg * 8;
        f32x4 u0 = *(const f32x4*)ap;
        f32x4 u1 = *(const f32x4*)(ap + 4);
        short8 a;
        a[0]=(short)f2bf(u0[0]); a[1]=(short)f2bf(u0[1]);
        a[2]=(short)f2bf(u0[2]); a[3]=(short)f2bf(u0[3]);
        a[4]=(short)f2bf(u1[0]); a[5]=(short)f2bf(u1[1]);
        a[6]=(short)f2bf(u1[2]); a[7]=(short)f2bf(u1[3]);
#pragma unroll
        for (int ct = 0; ct < 12; ++ct) {
            short8 b = *(const short8*)(WfghT + (ct*16 + lr) * C_ + kc*32 + lg*8);
            acc[ct] = __builtin_amdgcn_mfma_f32_16x16x32_bf16(a, b, acc[ct], 0, 0, 0);
        }
    }

#pragma unroll
    for (int ct = 0; ct < 12; ++ct) {
        int col = ct * 16 + lr;
        float bias = (col < DQK)   ? bf[col]
                   : (col < 2*DQK) ? bg[col - DQK]
                                   : bh[col - 2*DQK];
#pragma unroll
        for (int i = 0; i < 4; ++i) {
            int row = rb + lg * 4 + i;           // C layout: row=(lane>>4)*4+reg
            uint16_t h = f2bf(acc[ct][i] + bias);
            if (col < DQK) {
                fK[(size_t)row * DQK + col] = h;
            } else if (col < 2*DQK) {
                gQ[(size_t)row * DQK + (col - DQK)] = h;
            } else {
                int vc = col - 2*DQK;
                int nl = w * 16 + lg * 4 + i;    // n within block tile
                vlds[vc * 72 + nl] = h;
            }
        }
    }
    __syncthreads();
    // cooperative coalesced write: 128 vc-rows x 64 n (128B each)
    const int rb0   = blockIdx.x * 64;
    const int b_    = rb0 >> 12;
    const int nbase = rb0 & (N_ - 1);
    const int tid   = threadIdx.x;
#pragma unroll
    for (int pass = 0; pass < 4; ++pass) {
        int vc = pass * 32 + (tid >> 3);
        int nl = (tid & 7) * 8;
        short8 vv = *(const short8*)(vlds + vc * 72 + nl);
        *(short8*)(vT + ((size_t)b_ * DV + vc) * N_ + nbase + nl) = vv;
    }
}

// ---------------------------------------------------------------------------
// K2: flash attention, KV-split S (R1-proven COMPUTE + explicit P-LDS fence).
//     grid=256*S, 4 waves, 16 q-rows/wave, KV tiles of 64, double-buffered
//     global_load_lds staging, XOR-swizzled K/V slots (swizzle on SOURCE).
//     Writes UNNORMALIZED partial O (f32) + per-row m,l (f32).
// ---------------------------------------------------------------------------
template<int S>
__global__ __launch_bounds__(256) void attn_kernel(
    const uint16_t* __restrict__ fK, const uint16_t* __restrict__ gQ,
    const uint16_t* __restrict__ vT,
    float* __restrict__ opart, float* __restrict__ msplit,
    float* __restrict__ lsplit)
{
    __shared__ __align__(16) uint8_t lds[2*4096 + 2*16384 + 4*2304];  // 50176B
    uint8_t* Kl = lds;                    // 2 x 4 KB : K tiles [64 keys][32 d]
    uint8_t* Vl = lds + 2*4096;           // 2 x 16 KB: VT tiles [128 vc][64 keys]
    const int lane = threadIdx.x & 63;
    const int w    = threadIdx.x >> 6;
    uint8_t* Pl = lds + 2*4096 + 2*16384 + w * 2304;  // per-wave P [16][72]
    const int lr = lane & 15, lg = lane >> 4;

    const int bid   = blockIdx.x;
    const int xcd   = bid & 7;
    const int b     = xcd >> 1;                 // batch per XCD-pair
    const int t_    = bid >> 3;                 // 0 .. 32*S-1
    const int s     = t_ >> 5;                  // KV split id
    const int qtile = (xcd & 1) * 32 + (t_ & 31);
    const int qbase = qtile * QBLK;
    const int kv0   = s * (N_ / S);             // key range base
    const int NTS   = 64 / S;                   // KV tiles per split

    // Q A-frag (hoisted): row = lr, k = lg*8+j
    short8 aq = *(const short8*)(gQ + ((size_t)(b*N_ + qbase + w*16 + lr)) * DQK + lg*8);

    const f32x4 z = {0.f, 0.f, 0.f, 0.f};
    f32x4 oa[8];
#pragma unroll
    for (int i = 0; i < 8; ++i) oa[i] = z;
    float m_run[4] = {-1e30f, -1e30f, -1e30f, -1e30f};
    float l_run[4] = {0.f, 0.f, 0.f, 0.f};

    const uint16_t* fbase = fK + (size_t)b * N_ * DQK;
    const uint16_t* vbase = vT + (size_t)b * DV * N_;

    auto STAGE = [&](int buf, int kbase) {
        {
            int sl  = w * 64 + lane;
            int key = sl >> 2;
            int g   = (sl & 3) ^ ((key >> 1) & 3);
            const uint16_t* src = fbase + (size_t)(kbase + key) * DQK + g * 8;
            __builtin_amdgcn_global_load_lds(
                (const __attribute__((address_space(1))) uint32_t*)src,
                (__attribute__((address_space(3))) uint32_t*)(Kl + buf*4096 + w*1024),
                16, 0, 0);
        }
#pragma unroll
        for (int q = 0; q < 4; ++q) {
            int sl = w * 256 + q * 64 + lane;
            int vc = sl >> 3;
            int ks = (sl & 7) ^ (vc & 7);
            const uint16_t* src = vbase + (size_t)vc * N_ + kbase + ks * 8;
            __builtin_amdgcn_global_load_lds(
                (const __attribute__((address_space(1))) uint32_t*)src,
                (__attribute__((address_space(3))) uint32_t*)(Vl + buf*16384 + (w*256 + q*64)*16),
                16, 0, 0);
        }
    };

    auto COMPUTE = [&](int buf) {
        const uint8_t* Kb = Kl + buf * 4096;
        const uint8_t* Vb = Vl + buf * 16384;
        // S = Q K^T  (4 groups of 16 keys)
        f32x4 sf[4];
#pragma unroll
        for (int kg = 0; kg < 4; ++kg) {
            int key   = kg * 16 + lr;                       // B col = key
            int slotK = key * 4 + (lg ^ ((key >> 1) & 3));  // swizzled read
            short8 kb = *(const short8*)(Kb + slotK * 16);
            sf[kg] = __builtin_amdgcn_mfma_f32_16x16x32_bf16(aq, kb, z, 0, 0, 0);
        }
        // online softmax per row i (row = lg*4+i, spread over 16 lanes)
#pragma unroll
        for (int i = 0; i < 4; ++i) {
            float tm = fmaxf(fmaxf(sf[0][i], sf[1][i]), fmaxf(sf[2][i], sf[3][i]));
            tm = fmaxf(tm, __shfl_xor(tm, 1, 16));
            tm = fmaxf(tm, __shfl_xor(tm, 2, 16));
            tm = fmaxf(tm, __shfl_xor(tm, 4, 16));
            tm = fmaxf(tm, __shfl_xor(tm, 8, 16));
            float mn = fmaxf(m_run[i], tm);
            float sc = __expf(m_run[i] - mn);
            m_run[i] = mn;
            float rs = 0.f;
#pragma unroll
            for (int kg = 0; kg < 4; ++kg) {
                float p = __expf(sf[kg][i] - mn);
                sf[kg][i] = p;
                rs += p;
            }
            rs += __shfl_xor(rs, 1, 16);
            rs += __shfl_xor(rs, 2, 16);
            rs += __shfl_xor(rs, 4, 16);
            rs += __shfl_xor(rs, 8, 16);
            l_run[i] = l_run[i] * sc + rs;
#pragma unroll
            for (int ct = 0; ct < 8; ++ct) oa[ct][i] *= sc;
            // C-layout -> LDS (row = lg*4+i, col = kg*16+lr)
#pragma unroll
            for (int kg = 0; kg < 4; ++kg) {
                *(uint16_t*)(Pl + (lg*4 + i) * PROWB + (kg*16 + lr) * 2) = f2bf(sf[kg][i]);
            }
        }
        // FENCE: P rows are written by lane (lg,i) but read by lane lr — a
        // cross-lane LDS dependency the compiler's alias analysis may not see.
        // Pin all ds_writes before, drain lgkm, pin ds_reads after.
        __builtin_amdgcn_sched_barrier(0);
        asm volatile("s_waitcnt lgkmcnt(0)" ::: "memory");
        __builtin_amdgcn_sched_barrier(0);
        // PV: O += P[16x64] * V[64x128]
#pragma unroll
        for (int kc = 0; kc < 2; ++kc) {
            short8 pa = *(const short8*)(Pl + lr * PROWB + kc * 64 + lg * 16);
#pragma unroll
            for (int ct = 0; ct < 8; ++ct) {
                int vc    = ct * 16 + lr;
                int ks    = kc * 4 + lg;
                int slotV = vc * 8 + (ks ^ (vc & 7));
                short8 vb = *(const short8*)(Vb + slotV * 16);
                oa[ct] = __builtin_amdgcn_mfma_f32_16x16x32_bf16(pa, vb, oa[ct], 0, 0, 0);
            }
        }
    };

    STAGE(0, kv0);
    for (int t = 0; t < NTS; ++t) {
        if (t + 1 < NTS) {
            STAGE((t + 1) & 1, kv0 + (t + 1) * KVB);
            asm volatile("s_waitcnt vmcnt(5)" ::: "memory");
        } else {
            asm volatile("s_waitcnt vmcnt(0)" ::: "memory");
        }
        asm volatile("s_barrier" ::: "memory");
        COMPUTE(t & 1);
        asm volatile("s_barrier" ::: "memory");
    }

    // epilogue: store UNNORMALIZED partial O (f32) + m,l (f32)
#pragma unroll
    for (int i = 0; i < 4; ++i) {
        int grow = b * N_ + qbase + w * 16 + lg * 4 + i;
        float* op = opart + ((size_t)s * TOT + grow) * DV;
#pragma unroll
        for (int ct = 0; ct < 8; ++ct) {
            op[ct * 16 + lr] = oa[ct][i];
        }
        if (lr == 0) {
            msplit[s * TOT + grow] = m_run[i];
            lsplit[s * TOT + grow] = l_run[i];
        }
    }
}

// ---------------------------------------------------------------------------
// K3: combine KV-split partials (f32) + out = x + o @ Wv + bv
// ---------------------------------------------------------------------------
template<int S>
__global__ __launch_bounds__(256) void out_kernel(
    const float* __restrict__ opart, const float* __restrict__ msplit,
    const float* __restrict__ lsplit, const uint16_t* __restrict__ WvT,
    const float* __restrict__ x, const float* __restrict__ bv,
    float* __restrict__ out)
{
    const int lane = threadIdx.x & 63;
    const int w    = threadIdx.x >> 6;
    const int rb   = blockIdx.x * 64 + w * 16;
    const int lr   = lane & 15, lg = lane >> 4;
    const int row  = rb + lr;

    // per-row split weights  w_s = e^{m_s - m*} / L
    float wsn[S];
    {
        float ms[S], ls[S];
#pragma unroll
        for (int su = 0; su < S; ++su) {
            ms[su] = msplit[su * TOT + row];
            ls[su] = lsplit[su * TOT + row];
        }
        float mx = -1e30f;
#pragma unroll
        for (int su = 0; su < S; ++su) mx = fmaxf(mx, ms[su]);
        float L = 0.f;
#pragma unroll
        for (int su = 0; su < S; ++su) { wsn[su] = __expf(ms[su] - mx); L += wsn[su] * ls[su]; }
        float inv = 1.f / L;
#pragma unroll
        for (int su = 0; su < S; ++su) wsn[su] *= inv;
    }

    const f32x4 z = {0.f, 0.f, 0.f, 0.f};
    f32x4 acc[16];
#pragma unroll
    for (int i = 0; i < 16; ++i) acc[i] = z;

#pragma unroll
    for (int kc = 0; kc < 4; ++kc) {
        float af[8] = {0.f,0.f,0.f,0.f,0.f,0.f,0.f,0.f};
#pragma unroll
        for (int su = 0; su < S; ++su) {
            const float* ov = opart + ((size_t)su * TOT + row) * DV + kc*32 + lg*8;
            f32x4 o0 = *(const f32x4*)ov;
            f32x4 o1 = *(const f32x4*)(ov + 4);
#pragma unroll
            for (int j = 0; j < 4; ++j) {
                af[j]     += wsn[su] * o0[j];
                af[j + 4] += wsn[su] * o1[j];
            }
        }
        short8 a;
#pragma unroll
        for (int j = 0; j < 8; ++j) a[j] = (short)f2bf(af[j]);
#pragma unroll
        for (int ct = 0; ct < 16; ++ct) {
            short8 bfr = *(const short8*)(WvT + (ct*16 + lr) * DV + kc*32 + lg*8);
            acc[ct] = __builtin_amdgcn_mfma_f32_16x16x32_bf16(a, bfr, acc[ct], 0, 0, 0);
        }
    }
#pragma unroll
    for (int ct = 0; ct < 16; ++ct) {
        int col = ct * 16 + lr;
        float bb = bv[col];
#pragma unroll
        for (int i = 0; i < 4; ++i) {
            size_t idx = (size_t)(rb + lg*4 + i) * C_ + col;
            out[idx] = acc[ct][i] + bb + x[idx];
        }
    }
}

// ---------------------------------------------------------------------------
extern "C" void kernel_launch(void* const* d_in, const int* in_sizes, int n_in,
                              void* d_out, int out_size, void* d_ws, size_t ws_size,
                              hipStream_t stream)
{
    const float* x  = (const float*)d_in[0];
    const float* Wf = (const float*)d_in[1];
    const float* bf = (const float*)d_in[2];
    const float* Wg = (const float*)d_in[3];
    const float* bg = (const float*)d_in[4];
    const float* Wh = (const float*)d_in[5];
    const float* bh = (const float*)d_in[6];
    const float* Wv = (const float*)d_in[7];
    const float* bv = (const float*)d_in[8];
    float* out = (float*)d_out;

    const size_t fixed = (size_t)NCOL*C_*2 + (size_t)C_*DV*2
                       + 2*(size_t)TOT*DQK*2 + (size_t)B_*DV*N_*2;   // ~6.16 MB
    auto need = [&](size_t S){ return fixed + S*TOT*DV*4 + 2*S*TOT*4; };
    const int S = (ws_size >= need(4)) ? 4 : (ws_size >= need(2)) ? 2 : 1;

    uint8_t* ws = (uint8_t*)d_ws;
    size_t off = 0;
    uint16_t* WfghT = (uint16_t*)(ws + off); off += (size_t)NCOL * C_ * 2;
    uint16_t* WvT   = (uint16_t*)(ws + off); off += (size_t)C_ * DV * 2;
    uint16_t* fK    = (uint16_t*)(ws + off); off += (size_t)TOT * DQK * 2;
    uint16_t* gQ    = (uint16_t*)(ws + off); off += (size_t)TOT * DQK * 2;
    uint16_t* vT    = (uint16_t*)(ws + off); off += (size_t)B_ * DV * N_ * 2;
    float*    opart = (float*)(ws + off);    off += (size_t)S * TOT * DV * 4;
    float*    mspl  = (float*)(ws + off);    off += (size_t)S * TOT * 4;
    float*    lspl  = (float*)(ws + off);    off += (size_t)S * TOT * 4;

    prep_weights<<<320, 256, 0, stream>>>(Wf, Wg, Wh, Wv, WfghT, WvT);
    proj_kernel <<<256, 256, 0, stream>>>(x, WfghT, bf, bg, bh, fK, gQ, vT);
    switch (S) {
    case 4:
        attn_kernel<4><<<1024, 256, 0, stream>>>(fK, gQ, vT, opart, mspl, lspl);
        out_kernel<4> <<<256, 256, 0, stream>>>(opart, mspl, lspl, WvT, x, bv, out);
        break;
    case 2:
        attn_kernel<2><<<512, 256, 0, stream>>>(fK, gQ, vT, opart, mspl, lspl);
        out_kernel<2> <<<256, 256, 0, stream>>>(opart, mspl, lspl, WvT, x, bv, out);
        break;
    default:
        attn_kernel<1><<<256, 256, 0, stream>>>(fK, gQ, vT, opart, mspl, lspl);
        out_kernel<1> <<<256, 256, 0, stream>>>(opart, mspl, lspl, WvT, x, bv, out);
        break;
    }
}

// Round 11
// 173.147 us; speedup vs baseline: 1.4995x; 1.0790x over previous
//
#include <hip/hip_runtime.h>
#include <hip/hip_bf16.h>
#include <stdint.h>

typedef __attribute__((ext_vector_type(8))) short short8;
typedef __attribute__((ext_vector_type(4))) float f32x4;

#define B_   4
#define N_   4096
#define C_   256
#define DQK  32
#define DV   128
#define NCOL 192      // DQK + DQK + DV
#define KVB  64
#define TOT  (B_*N_)  // 16384 rows total
#define PROWB 144     // P_lds row stride in bytes (72 bf16; 2-way conflict max)

__device__ __forceinline__ uint16_t f2bf(float f) {
    uint32_t u = __float_as_uint(f);
    u += 0x7fffu + ((u >> 16) & 1u);   // RNE
    return (uint16_t)(u >> 16);
}

// ---------------------------------------------------------------------------
// K0: cast + transpose weights.  WfghT[192][256] bf16 (cols of Wf|Wg|Wh),
//     WvT[256][128] bf16 (cols of Wv).
// ---------------------------------------------------------------------------
__global__ __launch_bounds__(256) void prep_weights(
    const float* __restrict__ Wf, const float* __restrict__ Wg,
    const float* __restrict__ Wh, const float* __restrict__ Wv,
    uint16_t* __restrict__ WfghT, uint16_t* __restrict__ WvT)
{
    int idx = blockIdx.x * 256 + threadIdx.x;
    if (idx < NCOL * C_) {
        int c = idx / C_, k = idx % C_;
        float v = (c < DQK)   ? Wf[k * DQK + c]
                : (c < 2*DQK) ? Wg[k * DQK + (c - DQK)]
                              : Wh[k * DV  + (c - 2*DQK)];
        WfghT[idx] = f2bf(v);
    }
    int idx2 = idx - NCOL * C_;
    if (idx2 >= 0 && idx2 < C_ * DV) {
        int c = idx2 / DV, k = idx2 % DV;
        WvT[idx2] = f2bf(Wv[k * C_ + c]);
    }
}

// ---------------------------------------------------------------------------
// K1: projection GEMM, column-split: blocks [0,256) compute fK+gQ (cols 0-63),
//     blocks [256,512) compute vT (cols 64-191, via LDS transpose).
//     2 waves/SIMD (was 1).
// ---------------------------------------------------------------------------
__global__ __launch_bounds__(256) void proj_kernel(
    const float* __restrict__ x, const uint16_t* __restrict__ WfghT,
    const float* __restrict__ bf, const float* __restrict__ bg,
    const float* __restrict__ bh,
    uint16_t* __restrict__ fK, uint16_t* __restrict__ gQ,
    uint16_t* __restrict__ vT)
{
    __shared__ __align__(16) uint16_t vlds[128 * 72];   // [vc][n_local] pad 64->72
    const bool isV = blockIdx.x >= 256;
    const int bx   = isV ? blockIdx.x - 256 : blockIdx.x;
    const int lane = threadIdx.x & 63;
    const int w    = threadIdx.x >> 6;
    const int rb   = bx * 64 + w * 16;           // 16 rows per wave
    const int lr   = lane & 15, lg = lane >> 4;
    const int arow = rb + lr;

    const f32x4 z = {0.f, 0.f, 0.f, 0.f};
    f32x4 acc[8];
#pragma unroll
    for (int i = 0; i < 8; ++i) acc[i] = z;

#pragma unroll
    for (int kc = 0; kc < 8; ++kc) {
        const float* ap = x + (size_t)arow * C_ + kc * 32 + lg * 8;
        f32x4 u0 = *(const f32x4*)ap;
        f32x4 u1 = *(const f32x4*)(ap + 4);
        short8 a;
        a[0]=(short)f2bf(u0[0]); a[1]=(short)f2bf(u0[1]);
        a[2]=(short)f2bf(u0[2]); a[3]=(short)f2bf(u0[3]);
        a[4]=(short)f2bf(u1[0]); a[5]=(short)f2bf(u1[1]);
        a[6]=(short)f2bf(u1[2]); a[7]=(short)f2bf(u1[3]);
        if (isV) {
#pragma unroll
            for (int ct = 0; ct < 8; ++ct) {
                short8 b = *(const short8*)(WfghT + (64 + ct*16 + lr) * C_ + kc*32 + lg*8);
                acc[ct] = __builtin_amdgcn_mfma_f32_16x16x32_bf16(a, b, acc[ct], 0, 0, 0);
            }
        } else {
#pragma unroll
            for (int ct = 0; ct < 4; ++ct) {
                short8 b = *(const short8*)(WfghT + (ct*16 + lr) * C_ + kc*32 + lg*8);
                acc[ct] = __builtin_amdgcn_mfma_f32_16x16x32_bf16(a, b, acc[ct], 0, 0, 0);
            }
        }
    }

    if (!isV) {
        // fK (cols 0-31) + gQ (cols 32-63)
#pragma unroll
        for (int ct = 0; ct < 4; ++ct) {
            int col = ct * 16 + lr;
            float bias = (col < DQK) ? bf[col] : bg[col - DQK];
#pragma unroll
            for (int i = 0; i < 4; ++i) {
                int row = rb + lg * 4 + i;       // C layout: row=(lane>>4)*4+reg
                uint16_t h = f2bf(acc[ct][i] + bias);
                if (col < DQK) fK[(size_t)row * DQK + col] = h;
                else           gQ[(size_t)row * DQK + (col - DQK)] = h;
            }
        }
    } else {
        // vT (cols 64-191) via LDS transpose
#pragma unroll
        for (int ct = 0; ct < 8; ++ct) {
            int vc = ct * 16 + lr;               // 0..127
            float bias = bh[vc];
#pragma unroll
            for (int i = 0; i < 4; ++i) {
                int nl = w * 16 + lg * 4 + i;    // n within block tile
                vlds[vc * 72 + nl] = f2bf(acc[ct][i] + bias);
            }
        }
        __syncthreads();
        const int rb0   = bx * 64;
        const int b_    = rb0 >> 12;
        const int nbase = rb0 & (N_ - 1);
        const int tid   = threadIdx.x;
#pragma unroll
        for (int pass = 0; pass < 4; ++pass) {
            int vc = pass * 32 + (tid >> 3);
            int nl = (tid & 7) * 8;
            short8 vv = *(const short8*)(vlds + vc * 72 + nl);
            *(short8*)(vT + ((size_t)b_ * DV + vc) * N_ + nbase + nl) = vv;
        }
    }
}

// ---------------------------------------------------------------------------
// K2: flash attention, KV-split S.  8 waves/block (512 thr), grid = 128*S,
//     q-tile = 128 rows/block (16/wave).  LDS 59392B -> 2 blocks/CU exactly,
//     one dispatch round at S=4, 16 waves/CU.  COMPUTE internals = R10-proven
//     (incl. P-LDS fence).  Writes UNNORMALIZED partial O (f32) + m,l (f32).
// ---------------------------------------------------------------------------
template<int S>
__global__ __launch_bounds__(512) void attn_kernel(
    const uint16_t* __restrict__ fK, const uint16_t* __restrict__ gQ,
    const uint16_t* __restrict__ vT,
    float* __restrict__ opart, float* __restrict__ msplit,
    float* __restrict__ lsplit)
{
    __shared__ __align__(16) uint8_t lds[2*4096 + 2*16384 + 8*2304];  // 59392B
    uint8_t* Kl = lds;                    // 2 x 4 KB : K tiles [64 keys][32 d]
    uint8_t* Vl = lds + 2*4096;           // 2 x 16 KB: VT tiles [128 vc][64 keys]
    const int lane = threadIdx.x & 63;
    const int w    = threadIdx.x >> 6;    // 0..7
    uint8_t* Pl = lds + 2*4096 + 2*16384 + w * 2304;  // per-wave P [16][72]
    const int lr = lane & 15, lg = lane >> 4;

    const int bid  = blockIdx.x;
    const int xcd  = bid & 7;
    const int b    = xcd >> 1;                  // batch per XCD-pair
    const int rest = bid >> 3;                  // 0 .. 16*S-1
    const int s    = rest >> 4;                 // KV split id
    const int qtile= (xcd & 1) * 16 + (rest & 15);   // 0..31 (tiles of 128 rows)
    const int qbase= qtile * 128;
    const int kv0  = s * (N_ / S);              // key range base
    const int NTS  = 64 / S;                    // KV tiles per split

    // Q A-frag (hoisted): row = lr, k = lg*8+j
    short8 aq = *(const short8*)(gQ + ((size_t)(b*N_ + qbase + w*16 + lr)) * DQK + lg*8);

    const f32x4 z = {0.f, 0.f, 0.f, 0.f};
    f32x4 oa[8];
#pragma unroll
    for (int i = 0; i < 8; ++i) oa[i] = z;
    float m_run[4] = {-1e30f, -1e30f, -1e30f, -1e30f};
    float l_run[4] = {0.f, 0.f, 0.f, 0.f};

    const uint16_t* fbase = fK + (size_t)b * N_ * DQK;
    const uint16_t* vbase = vT + (size_t)b * DV * N_;

    // Every wave issues exactly 3 global_load_lds per STAGE:
    //   1 exec-masked K load (lanes 0-31) + 2 V loads  -> uniform vmcnt math.
    auto STAGE = [&](int buf, int kbase) {
        if (lane < 32) {
            int sl  = w * 32 + lane;            // 0..255 (K slots of 16B)
            int key = sl >> 2;
            int g   = (sl & 3) ^ ((key >> 1) & 3);
            const uint16_t* src = fbase + (size_t)(kbase + key) * DQK + g * 8;
            __builtin_amdgcn_global_load_lds(
                (const __attribute__((address_space(1))) uint32_t*)src,
                (__attribute__((address_space(3))) uint32_t*)(Kl + buf*4096 + w*512),
                16, 0, 0);
        }
#pragma unroll
        for (int q = 0; q < 2; ++q) {
            int sl = w * 128 + q * 64 + lane;   // 0..1023 (V slots of 16B)
            int vc = sl >> 3;
            int ks = (sl & 7) ^ (vc & 7);
            const uint16_t* src = vbase + (size_t)vc * N_ + kbase + ks * 8;
            __builtin_amdgcn_global_load_lds(
                (const __attribute__((address_space(1))) uint32_t*)src,
                (__attribute__((address_space(3))) uint32_t*)(Vl + buf*16384 + (w*128 + q*64)*16),
                16, 0, 0);
        }
    };

    auto COMPUTE = [&](int buf) {
        const uint8_t* Kb = Kl + buf * 4096;
        const uint8_t* Vb = Vl + buf * 16384;
        // S = Q K^T  (4 groups of 16 keys)
        f32x4 sf[4];
#pragma unroll
        for (int kg = 0; kg < 4; ++kg) {
            int key   = kg * 16 + lr;                       // B col = key
            int slotK = key * 4 + (lg ^ ((key >> 1) & 3));  // swizzled read
            short8 kb = *(const short8*)(Kb + slotK * 16);
            sf[kg] = __builtin_amdgcn_mfma_f32_16x16x32_bf16(aq, kb, z, 0, 0, 0);
        }
        // online softmax per row i (row = lg*4+i, spread over 16 lanes)
#pragma unroll
        for (int i = 0; i < 4; ++i) {
            float tm = fmaxf(fmaxf(sf[0][i], sf[1][i]), fmaxf(sf[2][i], sf[3][i]));
            tm = fmaxf(tm, __shfl_xor(tm, 1, 16));
            tm = fmaxf(tm, __shfl_xor(tm, 2, 16));
            tm = fmaxf(tm, __shfl_xor(tm, 4, 16));
            tm = fmaxf(tm, __shfl_xor(tm, 8, 16));
            float mn = fmaxf(m_run[i], tm);
            float sc = __expf(m_run[i] - mn);
            m_run[i] = mn;
            float rs = 0.f;
#pragma unroll
            for (int kg = 0; kg < 4; ++kg) {
                float p = __expf(sf[kg][i] - mn);
                sf[kg][i] = p;
                rs += p;
            }
            rs += __shfl_xor(rs, 1, 16);
            rs += __shfl_xor(rs, 2, 16);
            rs += __shfl_xor(rs, 4, 16);
            rs += __shfl_xor(rs, 8, 16);
            l_run[i] = l_run[i] * sc + rs;
#pragma unroll
            for (int ct = 0; ct < 8; ++ct) oa[ct][i] *= sc;
            // C-layout -> LDS (row = lg*4+i, col = kg*16+lr)
#pragma unroll
            for (int kg = 0; kg < 4; ++kg) {
                *(uint16_t*)(Pl + (lg*4 + i) * PROWB + (kg*16 + lr) * 2) = f2bf(sf[kg][i]);
            }
        }
        // FENCE: P rows are written by lane (lg,i) but read by lane lr — a
        // cross-lane LDS dependency the compiler's alias analysis may not see.
        __builtin_amdgcn_sched_barrier(0);
        asm volatile("s_waitcnt lgkmcnt(0)" ::: "memory");
        __builtin_amdgcn_sched_barrier(0);
        // PV: O += P[16x64] * V[64x128]
#pragma unroll
        for (int kc = 0; kc < 2; ++kc) {
            short8 pa = *(const short8*)(Pl + lr * PROWB + kc * 64 + lg * 16);
#pragma unroll
            for (int ct = 0; ct < 8; ++ct) {
                int vc    = ct * 16 + lr;
                int ks    = kc * 4 + lg;
                int slotV = vc * 8 + (ks ^ (vc & 7));
                short8 vb = *(const short8*)(Vb + slotV * 16);
                oa[ct] = __builtin_amdgcn_mfma_f32_16x16x32_bf16(pa, vb, oa[ct], 0, 0, 0);
            }
        }
    };

    STAGE(0, kv0);
    for (int t = 0; t < NTS; ++t) {
        if (t + 1 < NTS) {
            STAGE((t + 1) & 1, kv0 + (t + 1) * KVB);
            asm volatile("s_waitcnt vmcnt(3)" ::: "memory");  // stage(t) done; 3 in flight
        } else {
            asm volatile("s_waitcnt vmcnt(0)" ::: "memory");
        }
        asm volatile("s_barrier" ::: "memory");
        COMPUTE(t & 1);
        asm volatile("s_barrier" ::: "memory");
    }

    // epilogue: store UNNORMALIZED partial O (f32) + m,l (f32)
#pragma unroll
    for (int i = 0; i < 4; ++i) {
        int grow = b * N_ + qbase + w * 16 + lg * 4 + i;
        float* op = opart + ((size_t)s * TOT + grow) * DV;
#pragma unroll
        for (int ct = 0; ct < 8; ++ct) {
            op[ct * 16 + lr] = oa[ct][i];
        }
        if (lr == 0) {
            msplit[s * TOT + grow] = m_run[i];
            lsplit[s * TOT + grow] = l_run[i];
        }
    }
}

// ---------------------------------------------------------------------------
// K3: combine KV-split partials (f32) + out = x + o @ Wv + bv.
//     Column-split: grid 512, block bid does rows (bid>>1)*64.., cols (bid&1)*128..
// ---------------------------------------------------------------------------
template<int S>
__global__ __launch_bounds__(256) void out_kernel(
    const float* __restrict__ opart, const float* __restrict__ msplit,
    const float* __restrict__ lsplit, const uint16_t* __restrict__ WvT,
    const float* __restrict__ x, const float* __restrict__ bv,
    float* __restrict__ out)
{
    const int lane = threadIdx.x & 63;
    const int w    = threadIdx.x >> 6;
    const int rb   = (blockIdx.x >> 1) * 64 + w * 16;
    const int ch   = blockIdx.x & 1;            // column half (128 cols)
    const int lr   = lane & 15, lg = lane >> 4;
    const int row  = rb + lr;

    // per-row split weights  w_s = e^{m_s - m*} / L
    float wsn[S];
    {
        float ms[S], ls[S];
#pragma unroll
        for (int su = 0; su < S; ++su) {
            ms[su] = msplit[su * TOT + row];
            ls[su] = lsplit[su * TOT + row];
        }
        float mx = -1e30f;
#pragma unroll
        for (int su = 0; su < S; ++su) mx = fmaxf(mx, ms[su]);
        float L = 0.f;
#pragma unroll
        for (int su = 0; su < S; ++su) { wsn[su] = __expf(ms[su] - mx); L += wsn[su] * ls[su]; }
        float inv = 1.f / L;
#pragma unroll
        for (int su = 0; su < S; ++su) wsn[su] *= inv;
    }

    const f32x4 z = {0.f, 0.f, 0.f, 0.f};
    f32x4 acc[8];
#pragma unroll
    for (int i = 0; i < 8; ++i) acc[i] = z;

#pragma unroll
    for (int kc = 0; kc < 4; ++kc) {
        float af[8] = {0.f,0.f,0.f,0.f,0.f,0.f,0.f,0.f};
#pragma unroll
        for (int su = 0; su < S; ++su) {
            const float* ov = opart + ((size_t)su * TOT + row) * DV + kc*32 + lg*8;
            f32x4 o0 = *(const f32x4*)ov;
            f32x4 o1 = *(const f32x4*)(ov + 4);
#pragma unroll
            for (int j = 0; j < 4; ++j) {
                af[j]     += wsn[su] * o0[j];
                af[j + 4] += wsn[su] * o1[j];
            }
        }
        short8 a;
#pragma unroll
        for (int j = 0; j < 8; ++j) a[j] = (short)f2bf(af[j]);
#pragma unroll
        for (int ct = 0; ct < 8; ++ct) {
            int col = ch * 128 + ct * 16 + lr;
            short8 bfr = *(const short8*)(WvT + (size_t)col * DV + kc*32 + lg*8);
            acc[ct] = __builtin_amdgcn_mfma_f32_16x16x32_bf16(a, bfr, acc[ct], 0, 0, 0);
        }
    }
#pragma unroll
    for (int ct = 0; ct < 8; ++ct) {
        int col = ch * 128 + ct * 16 + lr;
        float bb = bv[col];
#pragma unroll
        for (int i = 0; i < 4; ++i) {
            size_t idx = (size_t)(rb + lg*4 + i) * C_ + col;
            out[idx] = acc[ct][i] + bb + x[idx];
        }
    }
}

// ---------------------------------------------------------------------------
extern "C" void kernel_launch(void* const* d_in, const int* in_sizes, int n_in,
                              void* d_out, int out_size, void* d_ws, size_t ws_size,
                              hipStream_t stream)
{
    const float* x  = (const float*)d_in[0];
    const float* Wf = (const float*)d_in[1];
    const float* bf = (const float*)d_in[2];
    const float* Wg = (const float*)d_in[3];
    const float* bg = (const float*)d_in[4];
    const float* Wh = (const float*)d_in[5];
    const float* bh = (const float*)d_in[6];
    const float* Wv = (const float*)d_in[7];
    const float* bv = (const float*)d_in[8];
    float* out = (float*)d_out;

    const size_t fixed = (size_t)NCOL*C_*2 + (size_t)C_*DV*2
                       + 2*(size_t)TOT*DQK*2 + (size_t)B_*DV*N_*2;   // ~6.16 MB
    auto need = [&](size_t S){ return fixed + S*TOT*DV*4 + 2*S*TOT*4; };
    const int S = (ws_size >= need(4)) ? 4 : (ws_size >= need(2)) ? 2 : 1;

    uint8_t* ws = (uint8_t*)d_ws;
    size_t off = 0;
    uint16_t* WfghT = (uint16_t*)(ws + off); off += (size_t)NCOL * C_ * 2;
    uint16_t* WvT   = (uint16_t*)(ws + off); off += (size_t)C_ * DV * 2;
    uint16_t* fK    = (uint16_t*)(ws + off); off += (size_t)TOT * DQK * 2;
    uint16_t* gQ    = (uint16_t*)(ws + off); off += (size_t)TOT * DQK * 2;
    uint16_t* vT    = (uint16_t*)(ws + off); off += (size_t)B_ * DV * N_ * 2;
    float*    opart = (float*)(ws + off);    off += (size_t)S * TOT * DV * 4;
    float*    mspl  = (float*)(ws + off);    off += (size_t)S * TOT * 4;
    float*    lspl  = (float*)(ws + off);    off += (size_t)S * TOT * 4;

    prep_weights<<<320, 256, 0, stream>>>(Wf, Wg, Wh, Wv, WfghT, WvT);
    proj_kernel <<<512, 256, 0, stream>>>(x, WfghT, bf, bg, bh, fK, gQ, vT);
    switch (S) {
    case 4:
        attn_kernel<4><<<512, 512, 0, stream>>>(fK, gQ, vT, opart, mspl, lspl);
        out_kernel<4> <<<512, 256, 0, stream>>>(opart, mspl, lspl, WvT, x, bv, out);
        break;
    case 2:
        attn_kernel<2><<<256, 512, 0, stream>>>(fK, gQ, vT, opart, mspl, lspl);
        out_kernel<2> <<<512, 256, 0, stream>>>(opart, mspl, lspl, WvT, x, bv, out);
        break;
    default:
        attn_kernel<1><<<128, 512, 0, stream>>>(fK, gQ, vT, opart, mspl, lspl);
        out_kernel<1> <<<512, 256, 0, stream>>>(opart, mspl, lspl, WvT, x, bv, out);
        break;
    }
}